// Round 1
// baseline (698.104 us; speedup 1.0000x reference)
//
#include <hip/hip_runtime.h>

// EHD layer: 3x3 x 8-orientation conv -> argmax+threshold -> 9-bin one-hot
// -> 5x5 box count / 25.
// R4: col remap j=4t+c (thread owns 4 consecutive cols).
//  - x loads: float4+float2 per row (was 12 scalar loads, 3x redundant)
//  - vertical 5-row ring in REGISTERS (rs was same-thread LDS round-trip)
//  - horizontal sums: own one-hots from regs + 4 neighbor u64 from LDS
//  - double-buffered ohrow -> 1 barrier/iter (was 2)
//  - float2 stores (row base only 8B-aligned; 4072B rows)
//  - RPB=16 -> 20/16 row redundancy, grid 64x16=1024 = exactly 4 blocks/CU

#define NOR 8
#define HH  1024
#define WW  1024
#define H2  1018
#define W2  1018
#define RPB 16
#define NIT (RPB + 4)

__global__ __launch_bounds__(256, 4)
void ehd_rows(const float* __restrict__ x,
              const float* __restrict__ masks,
              float* __restrict__ out)
{
    __shared__ unsigned long long oh[2][WW];   // packed one-hot, double-buffered

    const int t  = threadIdx.x;
    const int j0 = t * 4;                      // cols j0..j0+3
    const int r0 = blockIdx.x * RPB;
    const int b  = blockIdx.y;
    const float* xb = x + (long)b * HH * WW;

    // masks: thread-uniform -> scalar loads (SGPRs)
    float m[NOR][9];
#pragma unroll
    for (int o = 0; o < NOR; ++o)
#pragma unroll
        for (int k = 0; k < 9; ++k)
            m[o][k] = masks[o * 9 + k];

    // clamped start for the 2-col tail load (t=255 wraps to cols 1022,1023;
    // those values are exactly what conv cols 1020,1021 need)
    const int jc = (j0 + 4 > WW - 2) ? (WW - 2) : (j0 + 4);

    // register x-window: rows rr..rr+2, cols j0..j0+5
    float wr[3][6];
#pragma unroll
    for (int s = 0; s < 3; ++s) {
        const float4 a  = *reinterpret_cast<const float4*>(xb + (r0 + s) * WW + j0);
        const float2 bb = *reinterpret_cast<const float2*>(xb + (r0 + s) * WW + jc);
        wr[s][0] = a.x; wr[s][1] = a.y; wr[s][2] = a.z; wr[s][3] = a.w;
        wr[s][4] = bb.x; wr[s][5] = bb.y;
    }

    // vertical 5-row ring of horizontal 5-sums, in registers
    unsigned long long hs[5][4];
#pragma unroll
    for (int q = 0; q < 5; ++q)
#pragma unroll
        for (int c = 0; c < 4; ++c) hs[q][c] = 0ull;

    for (int rr = 0; rr < NIT; ++rr) {
        // ---- prefetch x row rr+3 (used next iteration)
        int nr = r0 + rr + 3; if (nr > HH - 1) nr = HH - 1;
        const float4 pa = *reinterpret_cast<const float4*>(xb + nr * WW + j0);
        const float2 pb = *reinterpret_cast<const float2*>(xb + nr * WW + jc);

        unsigned long long* ohc = oh[rr & 1];

        // ---- phase 1: conv -> argmax -> threshold -> packed one-hot
        unsigned long long ohv[4];
#pragma unroll
        for (int c = 0; c < 4; ++c) {
            float best = 0.0f; int bi = 0;
#pragma unroll
            for (int o = 0; o < NOR; ++o) {
                float acc = wr[0][c] * m[o][0];                 // same order as R2/R3
                acc = fmaf(wr[0][c + 1], m[o][1], acc);
                acc = fmaf(wr[0][c + 2], m[o][2], acc);
                acc = fmaf(wr[1][c    ], m[o][3], acc);
                acc = fmaf(wr[1][c + 1], m[o][4], acc);
                acc = fmaf(wr[1][c + 2], m[o][5], acc);
                acc = fmaf(wr[2][c    ], m[o][6], acc);
                acc = fmaf(wr[2][c + 1], m[o][7], acc);
                acc = fmaf(wr[2][c + 2], m[o][8], acc);
                if (o == 0)          { best = acc; }
                else if (acc > best) { best = acc; bi = o; }
            }
            if (best < 0.9f) bi = NOR;
            ohv[c] = 1ull << (7 * bi);
        }
        if (t < 255) {
#pragma unroll
            for (int c = 0; c < 4; ++c) ohc[j0 + c] = ohv[c];
        } else {
            // t=255: only conv cols 1020,1021 are valid/needed
            ohc[j0]     = ohv[0];
            ohc[j0 + 1] = ohv[1];
        }
        __syncthreads();

        // ---- phase 2: horizontal 5-sums (own 4 from regs, 4 neighbors from LDS)
        if (t < 255) {
            const unsigned long long o4 = ohc[j0 + 4];
            const unsigned long long o5 = ohc[j0 + 5];
            const unsigned long long o6 = ohc[j0 + 6];
            const unsigned long long o7 = ohc[j0 + 7];
            const unsigned long long s0 = ohv[0] + ohv[1] + ohv[2] + ohv[3] + o4;
            const unsigned long long s1 = s0 + o5 - ohv[0];   // 7-bit fields: no borrow
            const unsigned long long s2 = s1 + o6 - ohv[1];
            const unsigned long long s3 = s2 + o7 - ohv[2];

            // rotate ring (static indices -> stays in VGPRs)
#pragma unroll
            for (int q = 0; q < 4; ++q)
#pragma unroll
                for (int c = 0; c < 4; ++c) hs[q][c] = hs[q + 1][c];
            hs[4][0] = s0; hs[4][1] = s1; hs[4][2] = s2; hs[4][3] = s3;

            // ---- emit output row ro = r0+rr-4
            if (rr >= 4) {
                const int ro = r0 + rr - 4;
                if (ro < H2) {
                    const unsigned long long v0 = hs[0][0] + hs[1][0] + hs[2][0] + hs[3][0] + hs[4][0];
                    const unsigned long long v1 = hs[0][1] + hs[1][1] + hs[2][1] + hs[3][1] + hs[4][1];
                    const unsigned long long v2 = hs[0][2] + hs[1][2] + hs[2][2] + hs[3][2] + hs[4][2];
                    const unsigned long long v3 = hs[0][3] + hs[1][3] + hs[2][3] + hs[3][3] + hs[4][3];
                    float* op = out + ((long)b * 9 * H2 + (long)ro) * W2 + j0;
                    if (t < 254) {
#pragma unroll
                        for (int k = 0; k < 9; ++k) {
                            const float f0 = (float)((unsigned)(v0 >> (7 * k)) & 0x7Fu) * (1.0f / 25.0f);
                            const float f1 = (float)((unsigned)(v1 >> (7 * k)) & 0x7Fu) * (1.0f / 25.0f);
                            const float f2 = (float)((unsigned)(v2 >> (7 * k)) & 0x7Fu) * (1.0f / 25.0f);
                            const float f3 = (float)((unsigned)(v3 >> (7 * k)) & 0x7Fu) * (1.0f / 25.0f);
                            float2* q2 = reinterpret_cast<float2*>(op + (long)k * H2 * W2);
                            q2[0] = make_float2(f0, f1);
                            q2[1] = make_float2(f2, f3);
                        }
                    } else {
                        // t=254: cols 1016,1017 valid; 1018,1019 out of range
#pragma unroll
                        for (int k = 0; k < 9; ++k) {
                            const float f0 = (float)((unsigned)(v0 >> (7 * k)) & 0x7Fu) * (1.0f / 25.0f);
                            const float f1 = (float)((unsigned)(v1 >> (7 * k)) & 0x7Fu) * (1.0f / 25.0f);
                            float* q1 = op + (long)k * H2 * W2;
                            q1[0] = f0;
                            q1[1] = f1;
                        }
                    }
                }
            }
        }
        // no second barrier: next iteration writes the OTHER oh buffer; the
        // barrier above separates any two writers of the same buffer.

        // ---- rotate register x-window
#pragma unroll
        for (int d = 0; d < 6; ++d) {
            wr[0][d] = wr[1][d];
            wr[1][d] = wr[2][d];
        }
        wr[2][0] = pa.x; wr[2][1] = pa.y; wr[2][2] = pa.z; wr[2][3] = pa.w;
        wr[2][4] = pb.x; wr[2][5] = pb.y;
    }
}

extern "C" void kernel_launch(void* const* d_in, const int* in_sizes, int n_in,
                              void* d_out, int out_size, void* d_ws, size_t ws_size,
                              hipStream_t stream)
{
    const float* x     = (const float*)d_in[0];
    const float* masks = (const float*)d_in[1];
    float* out         = (float*)d_out;

    dim3 grid((H2 + RPB - 1) / RPB,   // 64 row stripes
              16);                    // batch
    ehd_rows<<<grid, 256, 0, stream>>>(x, masks, out);
}